// Round 1
// baseline (268.421 us; speedup 1.0000x reference)
//
#include <hip/hip_runtime.h>

// Problem: SmoothL1 word loss (packed mean) + sentence loss (per-batch time-means)
// preds/targets: [B=32, T=2048, D=512] fp32; decode_lengths: [32] int32; out: 1 fp32.
// BETA = 1.0  -> smooth_l1(d) = |d|<1 ? 0.5 d^2 : |d| - 0.5

#define BATCH 32
#define TLEN  2048
#define DDIM  512
#define ROWS_PER_BLOCK 32
#define P1_THREADS 128   // 128 threads x float4 = 512 columns

__device__ __forceinline__ float sl1(float d) {
    float ad = fabsf(d);
    return ad < 1.0f ? 0.5f * d * d : ad - 0.5f;
}

// Pass 1: per-(b,d) column sums of preds/targets over valid t, plus word-loss sum.
__global__ __launch_bounds__(P1_THREADS)
void pass1(const float* __restrict__ preds, const float* __restrict__ targs,
           const int* __restrict__ lens,
           float* __restrict__ colp, float* __restrict__ colt,
           float* __restrict__ wacc)
{
    const int b     = blockIdx.x;
    const int chunk = blockIdx.y;
    const int len   = lens[b];
    const int t0    = chunk * ROWS_PER_BLOCK;
    if (t0 >= len) return;                       // whole chunk masked out: skip reads
    const int t1 = min(t0 + ROWS_PER_BLOCK, len);

    const float4* __restrict__ p4 =
        (const float4*)(preds + (size_t)b * TLEN * DDIM);
    const float4* __restrict__ q4 =
        (const float4*)(targs + (size_t)b * TLEN * DDIM);
    const int lane4 = threadIdx.x;               // float4 index within a row

    float4 sp = make_float4(0.f, 0.f, 0.f, 0.f);
    float4 st = make_float4(0.f, 0.f, 0.f, 0.f);
    float  w  = 0.f;

    for (int t = t0; t < t1; ++t) {
        float4 p = p4[(size_t)t * (DDIM / 4) + lane4];
        float4 q = q4[(size_t)t * (DDIM / 4) + lane4];
        sp.x += p.x; sp.y += p.y; sp.z += p.z; sp.w += p.w;
        st.x += q.x; st.y += q.y; st.z += q.z; st.w += q.w;
        w += sl1(p.x - q.x) + sl1(p.y - q.y) + sl1(p.z - q.z) + sl1(p.w - q.w);
    }

    // Column-sum accumulation (64 KB arrays -> L2-resident atomics).
    float* cp = colp + b * DDIM + lane4 * 4;
    float* ct = colt + b * DDIM + lane4 * 4;
    atomicAdd(cp + 0, sp.x); atomicAdd(cp + 1, sp.y);
    atomicAdd(cp + 2, sp.z); atomicAdd(cp + 3, sp.w);
    atomicAdd(ct + 0, st.x); atomicAdd(ct + 1, st.y);
    atomicAdd(ct + 2, st.z); atomicAdd(ct + 3, st.w);

    // Word-loss: wave reduce (wave=64), then one atomic per block.
    #pragma unroll
    for (int off = 32; off; off >>= 1) w += __shfl_down(w, off);
    __shared__ float ws[P1_THREADS / 64];
    if ((threadIdx.x & 63) == 0) ws[threadIdx.x >> 6] = w;
    __syncthreads();
    if (threadIdx.x == 0) {
        float tot = 0.f;
        #pragma unroll
        for (int i = 0; i < P1_THREADS / 64; ++i) tot += ws[i];
        atomicAdd(wacc, tot);
    }
}

// Pass 2: fold column sums -> sentence loss; combine with word loss; write scalar.
__global__ __launch_bounds__(1024)
void pass2(const float* __restrict__ colp, const float* __restrict__ colt,
           const int* __restrict__ lens, const float* __restrict__ wacc,
           float* __restrict__ out)
{
    const int tid = threadIdx.x;
    float s = 0.f;
    for (int i = tid; i < BATCH * DDIM; i += 1024) {
        const int b = i >> 9;                    // i / DDIM
        const float L = (float)lens[b];
        const float d = (colp[i] - colt[i]) / L;
        s += sl1(d);
    }
    #pragma unroll
    for (int off = 32; off; off >>= 1) s += __shfl_down(s, off);
    __shared__ float red[16];
    if ((tid & 63) == 0) red[tid >> 6] = s;
    __syncthreads();
    if (tid == 0) {
        float sent = 0.f;
        #pragma unroll
        for (int i = 0; i < 16; ++i) sent += red[i];
        float nvalid = 0.f;
        for (int b = 0; b < BATCH; ++b) nvalid += (float)lens[b];
        const float word_loss = wacc[0] / (nvalid * (float)DDIM);
        const float sent_loss = sent / ((float)DDIM * (float)BATCH);
        out[0] = word_loss + sent_loss;
    }
}

extern "C" void kernel_launch(void* const* d_in, const int* in_sizes, int n_in,
                              void* d_out, int out_size, void* d_ws, size_t ws_size,
                              hipStream_t stream) {
    const float* preds = (const float*)d_in[0];
    const float* targs = (const float*)d_in[1];
    const int*   lens  = (const int*)d_in[2];
    float* out = (float*)d_out;

    // Workspace layout: colp [B*D], colt [B*D], wacc [1] — all fp32, zero-init.
    float* colp = (float*)d_ws;
    float* colt = colp + BATCH * DDIM;
    float* wacc = colt + BATCH * DDIM;
    const size_t ws_bytes = (size_t)(2 * BATCH * DDIM + 1) * sizeof(float);
    hipMemsetAsync(d_ws, 0, ws_bytes, stream);   // graph-capturable memset node

    dim3 grid1(BATCH, TLEN / ROWS_PER_BLOCK);
    pass1<<<grid1, P1_THREADS, 0, stream>>>(preds, targs, lens, colp, colt, wacc);
    pass2<<<1, 1024, 0, stream>>>(colp, colt, lens, wacc, out);
}